// Round 1
// baseline (2667.577 us; speedup 1.0000x reference)
//
#include <hip/hip_runtime.h>
#include <hip/hip_bf16.h>
#include <stdint.h>

#define Bb 32
#define Lx 512
#define Cc 256
#define Tt 4
#define HID 1024
#define RR (Bb*Lx)   // 16384 rows per timestep

// ---------------- Stage 1: conv(K=3 over L) + BN + LIF -> u8 spikes [T][R][C]
__global__ void conv_bn_lif(const float* __restrict__ x,
                            const float* __restrict__ cw,   // [T*3]
                            const float* __restrict__ cb,   // [T]
                            const float* __restrict__ g,
                            const float* __restrict__ be,
                            const float* __restrict__ mu,
                            const float* __restrict__ var,
                            uint8_t* __restrict__ spk) {
    int idx = blockIdx.x * blockDim.x + threadIdx.x;  // over B*L*C, c fastest
    if (idx >= Bb*Lx*Cc) return;
    int bl = idx / Cc;       // b*L + l
    int l  = bl % Lx;
    float x0 = x[idx];
    float xm = (l > 0)     ? x[idx - Cc] : 0.0f;
    float xp = (l < Lx-1)  ? x[idx + Cc] : 0.0f;
    float v = 0.0f;
    #pragma unroll
    for (int t = 0; t < Tt; ++t) {
        float y = cw[t*3+0]*xm + cw[t*3+1]*x0 + cw[t*3+2]*xp + cb[t];
        float inv = g[t] / sqrtf(var[t] + 1e-5f);
        y = (y - mu[t]) * inv + be[t];
        v = v + (y - v) * 0.5f;                 // TAU = 2
        float s = (v >= 1.0f) ? 1.0f : 0.0f;    // V_TH = 1
        spk[(size_t)t*(RR*Cc) + idx] = (uint8_t)s;
        v = v * (1.0f - s);                     // hard reset
    }
}

// ---------------- Fused 4-timestep GEMM + LIF epilogue
// A: u8 spikes [T][R][K], W: [N=HID][K] (k contiguous), bias: [HID]
// out: spikes u8 [T][R][HID]  (or, FINAL: fp32 mean-over-T [R][HID])
template<int K, bool FINAL>
__global__ __launch_bounds__(256)
void gemm4_lif(const uint8_t* __restrict__ A,
               const float* __restrict__ W,
               const float* __restrict__ bias,
               uint8_t* __restrict__ spk_out,
               float* __restrict__ out_mean) {
    __shared__ float As[Tt][16][64];   // [t][k][m]
    __shared__ float Bs[16][64];       // [k][n]
    const int NT = HID / 64;           // 16 n-tiles
    int mt = blockIdx.x / NT, nt = blockIdx.x % NT;
    int r0 = mt * 64, n0 = nt * 64;
    int tid = threadIdx.x;

    // staging maps
    int at  = tid >> 6;          // 0..3  (t)
    int am  = tid & 63;          // 0..63 (m)
    int bn_ = tid >> 2;          // 0..63 (n)
    int bk4 = (tid & 3) * 4;     // k chunk base
    // compute map: 16x16 threads, 4x4 micro-tile
    int tx = tid & 15, ty = tid >> 4;

    float acc[Tt][4][4] = {};

    for (int k0 = 0; k0 < K; k0 += 16) {
        // --- stage A (one 16-byte u8 row-chunk per thread)
        const uint8_t* ap = A + ((size_t)at * RR + (r0 + am)) * K + k0;
        uint4 av = *(const uint4*)ap;
        const uint8_t* ab = (const uint8_t*)&av;
        #pragma unroll
        for (int k = 0; k < 16; ++k) As[at][k][am] = (float)ab[k];
        // --- stage B (float4 along k, transpose into LDS)
        const float* wp = W + (size_t)(n0 + bn_) * K + k0 + bk4;
        float4 wv = *(const float4*)wp;
        Bs[bk4+0][bn_] = wv.x; Bs[bk4+1][bn_] = wv.y;
        Bs[bk4+2][bn_] = wv.z; Bs[bk4+3][bn_] = wv.w;
        __syncthreads();

        #pragma unroll
        for (int k = 0; k < 16; ++k) {
            float4 b4 = *(const float4*)&Bs[k][tx*4];
            float bv[4] = {b4.x, b4.y, b4.z, b4.w};
            #pragma unroll
            for (int t = 0; t < Tt; ++t) {
                float4 a4 = *(const float4*)&As[t][k][ty*4];
                float av_[4] = {a4.x, a4.y, a4.z, a4.w};
                #pragma unroll
                for (int m = 0; m < 4; ++m)
                    #pragma unroll
                    for (int n = 0; n < 4; ++n)
                        acc[t][m][n] += av_[m] * bv[n];
            }
        }
        __syncthreads();
    }

    // --- epilogue: bias + LIF across t (thread-local), emit spikes / mean
    #pragma unroll
    for (int m = 0; m < 4; ++m) {
        int r = r0 + ty*4 + m;
        #pragma unroll
        for (int n = 0; n < 4; ++n) {
            int nn = n0 + tx*4 + n;
            float bsv = bias[nn];
            float v = 0.0f, ssum = 0.0f;
            #pragma unroll
            for (int t = 0; t < Tt; ++t) {
                float xv = acc[t][m][n] + bsv;
                v = v + (xv - v) * 0.5f;
                float s = (v >= 1.0f) ? 1.0f : 0.0f;
                if constexpr (FINAL) {
                    ssum += s;
                } else {
                    spk_out[(size_t)t*RR*HID + (size_t)r*HID + nn] = (uint8_t)s;
                }
                v = v * (1.0f - s);
            }
            if constexpr (FINAL) {
                out_mean[(size_t)r*HID + nn] = ssum * 0.25f;
            }
        }
    }
}

// ---------------- out2[b,d] = mean over L of out1[b,l,d]  (exact: multiples of .25)
__global__ void mean_over_L(const float* __restrict__ out1, float* __restrict__ out2) {
    int idx = blockIdx.x * blockDim.x + threadIdx.x; // B*HID
    if (idx >= Bb*HID) return;
    int b = idx / HID, d = idx % HID;
    const float* p = out1 + (size_t)b*Lx*HID + d;
    float s = 0.0f;
    for (int l = 0; l < Lx; ++l) s += p[(size_t)l*HID];
    out2[idx] = s * (1.0f / Lx);
}

extern "C" void kernel_launch(void* const* d_in, const int* in_sizes, int n_in,
                              void* d_out, int out_size, void* d_ws, size_t ws_size,
                              hipStream_t stream) {
    const float* x      = (const float*)d_in[0];
    const float* cw     = (const float*)d_in[1];
    const float* cb     = (const float*)d_in[2];
    const float* g      = (const float*)d_in[3];
    const float* be     = (const float*)d_in[4];
    const float* mu     = (const float*)d_in[5];
    const float* var    = (const float*)d_in[6];
    const float* enc_w  = (const float*)d_in[7];
    const float* enc_b  = (const float*)d_in[8];
    const float* cell_w = (const float*)d_in[9];
    const float* cell_b = (const float*)d_in[10];

    float* out1 = (float*)d_out;                    // [R][HID]
    float* out2 = out1 + (size_t)RR * HID;          // [B][HID]

    uint8_t* ws   = (uint8_t*)d_ws;
    uint8_t* spk1 = ws;                                   // T*R*C   = 16 MB
    uint8_t* spkA = spk1 + (size_t)Tt * RR * Cc;          // T*R*HID = 64 MB
    uint8_t* spkB = spkA + (size_t)Tt * RR * HID;         // T*R*HID = 64 MB

    conv_bn_lif<<<(Bb*Lx*Cc + 255) / 256, 256, 0, stream>>>(
        x, cw, cb, g, be, mu, var, spk1);

    // enc: K=256
    gemm4_lif<Cc,  false><<<(RR/64)*(HID/64), 256, 0, stream>>>(
        spk1, enc_w, enc_b, spkA, nullptr);
    // cell 0: K=1024
    gemm4_lif<HID, false><<<(RR/64)*(HID/64), 256, 0, stream>>>(
        spkA, cell_w, cell_b, spkB, nullptr);
    // cell 1 (final): K=1024, fused mean over T
    gemm4_lif<HID, true><<<(RR/64)*(HID/64), 256, 0, stream>>>(
        spkB, cell_w + (size_t)HID*HID, cell_b + HID, nullptr, out1);

    mean_over_L<<<(Bb*HID + 255) / 256, 256, 0, stream>>>(out1, out2);
}

// Round 2
// 934.273 us; speedup vs baseline: 2.8552x; 2.8552x over previous
//
#include <hip/hip_runtime.h>
#include <hip/hip_bf16.h>
#include <stdint.h>

#define Bb 32
#define Lx 512
#define Cc 256
#define Tt 4
#define HID 1024
#define RR (Bb*Lx)          // 16384 logical rows (b*L+l)
#define CH 4096             // rows r per chunk
#define MR (CH*Tt)          // 16384 interleaved rows (r*4+t) per chunk
#define NCHUNK (RR/CH)      // 4

typedef _Float16 half8 __attribute__((ext_vector_type(8)));
typedef float f32x4 __attribute__((ext_vector_type(4)));

// ---------------- weight split: w = hi + lo/2048 (exact to 2^-23 rel)
__global__ void split_w(const float* __restrict__ w, _Float16* __restrict__ hi,
                        _Float16* __restrict__ lo, int n) {
    int i = blockIdx.x * 256 + threadIdx.x;
    if (i >= n) return;
    float x = w[i];
    _Float16 h = (_Float16)x;
    hi[i] = h;
    lo[i] = (_Float16)((x - (float)h) * 2048.0f);
}

// ---------------- Stage 1: conv(K=3 over L) + BN + LIF -> f16 spikes, rows r*4+t
__global__ void conv_bn_lif(const float* __restrict__ x,
                            const float* __restrict__ cw, const float* __restrict__ cb,
                            const float* __restrict__ g,  const float* __restrict__ be,
                            const float* __restrict__ mu, const float* __restrict__ var,
                            _Float16* __restrict__ spk) {   // [RR*4][Cc]
    int idx = blockIdx.x * blockDim.x + threadIdx.x;  // over B*L*C, c fastest
    if (idx >= Bb*Lx*Cc) return;
    int bl = idx / Cc;       // r = b*L + l
    int c  = idx % Cc;
    int l  = bl % Lx;
    float x0 = x[idx];
    float xm = (l > 0)    ? x[idx - Cc] : 0.0f;
    float xp = (l < Lx-1) ? x[idx + Cc] : 0.0f;
    float v = 0.0f;
    #pragma unroll
    for (int t = 0; t < Tt; ++t) {
        float y = cw[t*3+0]*xm + cw[t*3+1]*x0 + cw[t*3+2]*xp + cb[t];
        float inv = g[t] / sqrtf(var[t] + 1e-5f);
        y = (y - mu[t]) * inv + be[t];
        v = v + (y - v) * 0.5f;
        float s = (v >= 1.0f) ? 1.0f : 0.0f;
        spk[(size_t)(bl*4 + t)*Cc + c] = (_Float16)s;
        v = v * (1.0f - s);
    }
}

// ---------------- fused GEMM (A=f16 spikes, W split hi/lo) + LIF epilogue
// A: [MR][K] rows interleaved r*4+t. W*: [HID][K]. out: spikes f16 [MR][HID]
// or (FINAL) f32 mean-over-t [CH][HID].
template<int K, bool FINAL>
__global__ __launch_bounds__(256)
void gemm_lif(const _Float16* __restrict__ A,
              const _Float16* __restrict__ Whi, const _Float16* __restrict__ Wlo,
              const float* __restrict__ bias,
              _Float16* __restrict__ spk_out, float* __restrict__ out_mean) {
    // 128x128 tile, BK=32, padded LDS rows of 40 halfs (80 B) -> conflict-free reads
    __shared__ __align__(16) _Float16 As[128*40];
    __shared__ __align__(16) _Float16 Bs[128*40];
    const int tid  = threadIdx.x;
    const int wid  = tid >> 6, lane = tid & 63;
    const int wm   = wid >> 1, wn = wid & 1;        // 2x2 wave grid, 64x64 per wave
    const int m0   = blockIdx.x * 128;
    const int n0   = blockIdx.y * 128;
    const int srow = tid >> 2, sslot = tid & 3;     // staging map
    const int kq   = (lane >> 4) * 8;               // frag k-offset (in halfs)

    f32x4 acc[4][4] = {};

    #pragma unroll
    for (int pass = 0; pass < 2; ++pass) {
        const _Float16* W = pass ? Wlo : Whi;
        for (int k0 = 0; k0 < K; k0 += 32) {
            // ---- stage A & B tiles (reg-staged, 16B per thread per row-half)
            float4 a0 = *(const float4*)(A + (size_t)(m0 + srow)      * K + k0 + sslot*8);
            float4 a1 = *(const float4*)(A + (size_t)(m0 + 64 + srow) * K + k0 + sslot*8);
            float4 b0 = *(const float4*)(W + (size_t)(n0 + srow)      * K + k0 + sslot*8);
            float4 b1 = *(const float4*)(W + (size_t)(n0 + 64 + srow) * K + k0 + sslot*8);
            *(float4*)&As[(srow)      * 40 + sslot*8] = a0;
            *(float4*)&As[(64 + srow) * 40 + sslot*8] = a1;
            *(float4*)&Bs[(srow)      * 40 + sslot*8] = b0;
            *(float4*)&Bs[(64 + srow) * 40 + sslot*8] = b1;
            __syncthreads();
            // ---- fragments + MFMA
            half8 af[4], bf[4];
            #pragma unroll
            for (int i = 0; i < 4; ++i)
                af[i] = *(const half8*)&As[(wm*64 + i*16 + (lane & 15)) * 40 + kq];
            #pragma unroll
            for (int j = 0; j < 4; ++j)
                bf[j] = *(const half8*)&Bs[(wn*64 + j*16 + (lane & 15)) * 40 + kq];
            #pragma unroll
            for (int i = 0; i < 4; ++i)
                #pragma unroll
                for (int j = 0; j < 4; ++j)
                    acc[i][j] = __builtin_amdgcn_mfma_f32_16x16x32_f16(af[i], bf[j], acc[i][j], 0, 0, 0);
            __syncthreads();
        }
        if (pass == 0) {
            #pragma unroll
            for (int i = 0; i < 4; ++i)
                #pragma unroll
                for (int j = 0; j < 4; ++j)
                    acc[i][j] = acc[i][j] * 2048.0f;
        }
    }

    // ---- epilogue: per-lane LIF over the 4 regs (= 4 timesteps of one row)
    const int rowq = (lane >> 4) * 4;
    float bs[4];
    #pragma unroll
    for (int j = 0; j < 4; ++j)
        bs[j] = bias[n0 + wn*64 + j*16 + (lane & 15)];
    #pragma unroll
    for (int i = 0; i < 4; ++i) {
        int rowLocal = m0 + wm*64 + i*16 + rowq;    // interleaved row of reg 0 (t=0)
        int r = rowLocal >> 2;                      // chunk-local r
        #pragma unroll
        for (int j = 0; j < 4; ++j) {
            int n = n0 + wn*64 + j*16 + (lane & 15);
            float v = 0.0f, ssum = 0.0f;
            #pragma unroll
            for (int t = 0; t < 4; ++t) {
                float xv = acc[i][j][t] * (1.0f/2048.0f) + bs[j];
                v = v + (xv - v) * 0.5f;
                float s = (v >= 1.0f) ? 1.0f : 0.0f;
                if constexpr (FINAL) ssum += s;
                else spk_out[(size_t)(rowLocal + t) * HID + n] = (_Float16)s;
                v = v * (1.0f - s);
            }
            if constexpr (FINAL) out_mean[(size_t)r * HID + n] = ssum * 0.25f;
        }
    }
}

// ---------------- out2[b,d] = mean over L of out1[b,l,d]
__global__ void mean_over_L(const float* __restrict__ out1, float* __restrict__ out2) {
    int idx = blockIdx.x * blockDim.x + threadIdx.x; // B*HID
    if (idx >= Bb*HID) return;
    int b = idx / HID, d = idx % HID;
    const float* p = out1 + (size_t)b*Lx*HID + d;
    float s = 0.0f;
    for (int l = 0; l < Lx; ++l) s += p[(size_t)l*HID];
    out2[idx] = s * (1.0f / Lx);
}

extern "C" void kernel_launch(void* const* d_in, const int* in_sizes, int n_in,
                              void* d_out, int out_size, void* d_ws, size_t ws_size,
                              hipStream_t stream) {
    const float* x      = (const float*)d_in[0];
    const float* cw     = (const float*)d_in[1];
    const float* cb     = (const float*)d_in[2];
    const float* g      = (const float*)d_in[3];
    const float* be     = (const float*)d_in[4];
    const float* mu     = (const float*)d_in[5];
    const float* var    = (const float*)d_in[6];
    const float* enc_w  = (const float*)d_in[7];
    const float* enc_b  = (const float*)d_in[8];
    const float* cell_w = (const float*)d_in[9];
    const float* cell_b = (const float*)d_in[10];

    float* out1 = (float*)d_out;                    // [RR][HID]
    float* out2 = out1 + (size_t)RR * HID;          // [B][HID]

    // ---- ws layout (bytes): all within 105 MB
    uint8_t* ws = (uint8_t*)d_ws;
    _Float16* spk1 = (_Float16*)ws;                               // RR*4*Cc   f16 = 32 MB
    _Float16* spkA = (_Float16*)(ws + (size_t)32*1024*1024);      // MR*HID    f16 = 32 MB
    _Float16* spkB = (_Float16*)(ws + (size_t)64*1024*1024);      // MR*HID    f16 = 32 MB
    _Float16* wsp  = (_Float16*)(ws + (size_t)96*1024*1024);
    _Float16* encHi = wsp;                       // 1024*256
    _Float16* encLo = encHi + HID*Cc;
    _Float16* c0Hi  = encLo + HID*Cc;            // 1024*1024 each
    _Float16* c0Lo  = c0Hi + HID*HID;
    _Float16* c1Hi  = c0Lo + HID*HID;
    _Float16* c1Lo  = c1Hi + HID*HID;

    // ---- weight splits
    split_w<<<(HID*Cc + 255)/256, 256, 0, stream>>>(enc_w, encHi, encLo, HID*Cc);
    split_w<<<(HID*HID + 255)/256, 256, 0, stream>>>(cell_w, c0Hi, c0Lo, HID*HID);
    split_w<<<(HID*HID + 255)/256, 256, 0, stream>>>(cell_w + (size_t)HID*HID, c1Hi, c1Lo, HID*HID);

    // ---- conv + BN + LIF
    conv_bn_lif<<<(Bb*Lx*Cc + 255)/256, 256, 0, stream>>>(x, cw, cb, g, be, mu, var, spk1);

    // ---- chunked trunk
    dim3 grid(MR/128, HID/128);
    for (int c = 0; c < NCHUNK; ++c) {
        const _Float16* a1 = spk1 + (size_t)c * MR * Cc;
        gemm_lif<Cc,  false><<<grid, 256, 0, stream>>>(a1,   encHi, encLo, enc_b,       spkA, nullptr);
        gemm_lif<HID, false><<<grid, 256, 0, stream>>>(spkA, c0Hi,  c0Lo,  cell_b,      spkB, nullptr);
        gemm_lif<HID, true ><<<grid, 256, 0, stream>>>(spkB, c1Hi,  c1Lo,  cell_b+HID,  nullptr,
                                                       out1 + (size_t)c * CH * HID);
    }

    mean_over_L<<<(Bb*HID + 255)/256, 256, 0, stream>>>(out1, out2);
}

// Round 3
// 655.941 us; speedup vs baseline: 4.0668x; 1.4243x over previous
//
#include <hip/hip_runtime.h>
#include <hip/hip_bf16.h>
#include <stdint.h>

#define Bb 32
#define Lx 512
#define Cc 256
#define Tt 4
#define HID 1024
#define RR (Bb*Lx)          // 16384 logical rows (b*L+l)
#define CH 4096             // rows r per chunk
#define MR (CH*Tt)          // 16384 interleaved rows (r*4+t) per chunk
#define NCHUNK (RR/CH)      // 4

typedef _Float16 half8 __attribute__((ext_vector_type(8)));
typedef float f32x4 __attribute__((ext_vector_type(4)));

// ---------------- async global->LDS, 16B per lane
__device__ __forceinline__ void gl16(const void* g, void* l) {
    __builtin_amdgcn_global_load_lds(
        (const __attribute__((address_space(1))) unsigned int*)g,
        (__attribute__((address_space(3))) unsigned int*)l, 16, 0, 0);
}
__device__ __forceinline__ void blockbar() {
    asm volatile("" ::: "memory");
    __builtin_amdgcn_s_barrier();
    asm volatile("" ::: "memory");
}

// stage one 256x32 f16 tile (A or B panel) into LDS, linear dest, src pre-swizzled
// so that reads at slot' = slot ^ (row&3) see logical data (rule #21).
__device__ __forceinline__ void stage_tile(const _Float16* __restrict__ g, int K_,
                                           int rowBase, int ko,
                                           _Float16* ldst, int tid) {
    const int row  = tid >> 2;               // 0..127
    const int sslt = (tid & 3) ^ (row & 3);  // swizzled source slot
    #pragma unroll
    for (int i = 0; i < 2; ++i) {
        const _Float16* src = g + (size_t)(rowBase + i*128 + row) * K_ + ko + sslt*8;
        gl16((const void*)src, (void*)(ldst + i*4096 + (size_t)tid*8));
    }
}

// ---------------- weight split: w = hi + lo/2048 (exact to ~2^-22 rel)
__global__ void split_w(const float* __restrict__ w, _Float16* __restrict__ hi,
                        _Float16* __restrict__ lo, int n) {
    int i = blockIdx.x * 256 + threadIdx.x;
    if (i >= n) return;
    float x = w[i];
    _Float16 h = (_Float16)x;
    hi[i] = h;
    lo[i] = (_Float16)((x - (float)h) * 2048.0f);
}

// ---------------- Stage 1: conv(K=3 over L) + BN + LIF -> f16 spikes, rows r*4+t
__global__ void conv_bn_lif(const float* __restrict__ x,
                            const float* __restrict__ cw, const float* __restrict__ cb,
                            const float* __restrict__ g,  const float* __restrict__ be,
                            const float* __restrict__ mu, const float* __restrict__ var,
                            _Float16* __restrict__ spk) {   // [RR*4][Cc]
    int idx = blockIdx.x * blockDim.x + threadIdx.x;
    if (idx >= Bb*Lx*Cc) return;
    int bl = idx / Cc;
    int c  = idx % Cc;
    int l  = bl % Lx;
    float x0 = x[idx];
    float xm = (l > 0)    ? x[idx - Cc] : 0.0f;
    float xp = (l < Lx-1) ? x[idx + Cc] : 0.0f;
    float v = 0.0f;
    #pragma unroll
    for (int t = 0; t < Tt; ++t) {
        float y = cw[t*3+0]*xm + cw[t*3+1]*x0 + cw[t*3+2]*xp + cb[t];
        float inv = g[t] / sqrtf(var[t] + 1e-5f);
        y = (y - mu[t]) * inv + be[t];
        v = v + (y - v) * 0.5f;
        float s = (v >= 1.0f) ? 1.0f : 0.0f;
        spk[(size_t)(bl*4 + t)*Cc + c] = (_Float16)s;
        v = v * (1.0f - s);
    }
}

// ---------------- deep-pipelined fused GEMM (hi/lo passes) + LIF epilogue
// Tile 256x256, BK=32, 8 waves (2M x 4N), per-wave 128x64.
// Quad-buffered LDS, prefetch 3, counted vmcnt(8), one raw barrier per K-tile.
template<int K, bool FINAL>
__global__ __launch_bounds__(512, 2)
void gemm_lif(const _Float16* __restrict__ A,
              const _Float16* __restrict__ Whi, const _Float16* __restrict__ Wlo,
              const float* __restrict__ bias,
              _Float16* __restrict__ spk_out, float* __restrict__ out_mean) {
    constexpr int KT  = K / 32;           // K-tiles per pass
    constexpr int NKT = 2 * KT;           // hi pass then lo pass
    __shared__ _Float16 lds[4 * 2 * 8192];   // 4 bufs x (A,B) x 256x32 = 128 KB

    const int tid  = threadIdx.x;
    const int lane = tid & 63;
    const int wid  = tid >> 6;
    const int wm   = wid >> 2;        // 0..1
    const int wn   = wid & 3;         // 0..3
    const int m0   = blockIdx.x * 256;
    const int n0   = blockIdx.y * 256;

    const int fr = lane & 15;
    const int sw = (((lane >> 4) ^ (lane & 3)) << 3);  // swizzled k-offset (halfs)

    f32x4 acc[8][4] = {};

    // ---- prologue: stage tiles 0,1,2
    #pragma unroll
    for (int t = 0; t < 3; ++t) {
        const _Float16* W = (t >= KT) ? Wlo : Whi;
        int ko = (t >= KT ? t - KT : t) * 32;
        stage_tile(A, K, m0, ko, &lds[(t & 3) * 16384],        tid);
        stage_tile(W, K, n0, ko, &lds[(t & 3) * 16384 + 8192], tid);
    }

    #pragma unroll 1
    for (int kt = 0; kt < NKT; ++kt) {
        if (kt == KT) {   // pass boundary: finished hi accumulation
            #pragma unroll
            for (int i = 0; i < 8; ++i)
                #pragma unroll
                for (int j = 0; j < 4; ++j)
                    acc[i][j] *= 2048.0f;
        }
        if (kt < NKT-2)       asm volatile("s_waitcnt vmcnt(8)" ::: "memory");
        else if (kt == NKT-2) asm volatile("s_waitcnt vmcnt(4)" ::: "memory");
        else                  asm volatile("s_waitcnt vmcnt(0)" ::: "memory");
        blockbar();

        const _Float16* lA = &lds[(kt & 3) * 16384];
        const _Float16* lB = lA + 8192;
        const int tp = kt + 3;
        const bool pre = (tp < NKT);
        const _Float16* Wp = (tp >= KT) ? Wlo : Whi;
        const int kop = (tp >= KT ? tp - KT : tp) * 32;

        // ---- phase 1: stage A(kt+3) | read A frags + B(j=0,1) | 16 MFMA
        if (pre) stage_tile(A, K, m0, kop, &lds[(tp & 3) * 16384], tid);
        half8 af[8], bf[4];
        #pragma unroll
        for (int i = 0; i < 8; ++i)
            af[i] = *(const half8*)&lA[(wm*128 + i*16 + fr) * 32 + sw];
        #pragma unroll
        for (int j = 0; j < 2; ++j)
            bf[j] = *(const half8*)&lB[(wn*64 + j*16 + fr) * 32 + sw];
        __builtin_amdgcn_s_setprio(1);
        #pragma unroll
        for (int i = 0; i < 8; ++i)
            #pragma unroll
            for (int j = 0; j < 2; ++j)
                acc[i][j] = __builtin_amdgcn_mfma_f32_16x16x32_f16(af[i], bf[j], acc[i][j], 0, 0, 0);
        __builtin_amdgcn_s_setprio(0);

        // ---- phase 2: stage B(kt+3) | read B(j=2,3) | 16 MFMA (A reused)
        if (pre) stage_tile(Wp, K, n0, kop, &lds[(tp & 3) * 16384 + 8192], tid);
        #pragma unroll
        for (int j = 2; j < 4; ++j)
            bf[j] = *(const half8*)&lB[(wn*64 + j*16 + fr) * 32 + sw];
        __builtin_amdgcn_s_setprio(1);
        #pragma unroll
        for (int i = 0; i < 8; ++i)
            #pragma unroll
            for (int j = 2; j < 4; ++j)
                acc[i][j] = __builtin_amdgcn_mfma_f32_16x16x32_f16(af[i], bf[j], acc[i][j], 0, 0, 0);
        __builtin_amdgcn_s_setprio(0);
    }

    // ---- epilogue: per-lane LIF over 4 acc regs (= 4 timesteps of one row)
    float bs[4];
    #pragma unroll
    for (int j = 0; j < 4; ++j)
        bs[j] = bias[n0 + wn*64 + j*16 + fr];
    const int rowq = (lane >> 4) * 4;
    #pragma unroll
    for (int i = 0; i < 8; ++i) {
        int rowLocal = m0 + wm*128 + i*16 + rowq;   // t=0 row; rows rowLocal..+3 = t 0..3
        int r = rowLocal >> 2;
        #pragma unroll
        for (int j = 0; j < 4; ++j) {
            int n = n0 + wn*64 + j*16 + fr;
            float v = 0.0f, ssum = 0.0f;
            #pragma unroll
            for (int t = 0; t < 4; ++t) {
                float xv = acc[i][j][t] * (1.0f/2048.0f) + bs[j];
                v = v + (xv - v) * 0.5f;
                float s = (v >= 1.0f) ? 1.0f : 0.0f;
                if constexpr (FINAL) ssum += s;
                else spk_out[(size_t)(rowLocal + t) * HID + n] = (_Float16)s;
                v = v * (1.0f - s);
            }
            if constexpr (FINAL) out_mean[(size_t)r * HID + n] = ssum * 0.25f;
        }
    }
}

// ---------------- out2[b,d] = mean over L of out1[b,l,d]
__global__ void mean_over_L(const float* __restrict__ out1, float* __restrict__ out2) {
    int idx = blockIdx.x * blockDim.x + threadIdx.x; // B*HID
    if (idx >= Bb*HID) return;
    int b = idx / HID, d = idx % HID;
    const float* p = out1 + (size_t)b*Lx*HID + d;
    float s = 0.0f;
    for (int l = 0; l < Lx; ++l) s += p[(size_t)l*HID];
    out2[idx] = s * (1.0f / Lx);
}

extern "C" void kernel_launch(void* const* d_in, const int* in_sizes, int n_in,
                              void* d_out, int out_size, void* d_ws, size_t ws_size,
                              hipStream_t stream) {
    const float* x      = (const float*)d_in[0];
    const float* cw     = (const float*)d_in[1];
    const float* cb     = (const float*)d_in[2];
    const float* g      = (const float*)d_in[3];
    const float* be     = (const float*)d_in[4];
    const float* mu     = (const float*)d_in[5];
    const float* var    = (const float*)d_in[6];
    const float* enc_w  = (const float*)d_in[7];
    const float* enc_b  = (const float*)d_in[8];
    const float* cell_w = (const float*)d_in[9];
    const float* cell_b = (const float*)d_in[10];

    float* out1 = (float*)d_out;                    // [RR][HID]
    float* out2 = out1 + (size_t)RR * HID;          // [B][HID]

    // ---- ws layout
    uint8_t* ws = (uint8_t*)d_ws;
    _Float16* spk1 = (_Float16*)ws;                               // RR*4*Cc f16 = 32 MB
    _Float16* spkA = (_Float16*)(ws + (size_t)32*1024*1024);      // MR*HID  f16 = 32 MB
    _Float16* spkB = (_Float16*)(ws + (size_t)64*1024*1024);      // MR*HID  f16 = 32 MB
    _Float16* wsp  = (_Float16*)(ws + (size_t)96*1024*1024);
    _Float16* encHi = wsp;                       // 1024*256
    _Float16* encLo = encHi + HID*Cc;
    _Float16* c0Hi  = encLo + HID*Cc;            // 1024*1024 each
    _Float16* c0Lo  = c0Hi + HID*HID;
    _Float16* c1Hi  = c0Lo + HID*HID;
    _Float16* c1Lo  = c1Hi + HID*HID;

    split_w<<<(HID*Cc + 255)/256, 256, 0, stream>>>(enc_w, encHi, encLo, HID*Cc);
    split_w<<<(HID*HID + 255)/256, 256, 0, stream>>>(cell_w, c0Hi, c0Lo, HID*HID);
    split_w<<<(HID*HID + 255)/256, 256, 0, stream>>>(cell_w + (size_t)HID*HID, c1Hi, c1Lo, HID*HID);

    conv_bn_lif<<<(Bb*Lx*Cc + 255)/256, 256, 0, stream>>>(x, cw, cb, g, be, mu, var, spk1);

    dim3 grid(MR/256, HID/256);   // 64 x 4 = 256 blocks
    for (int c = 0; c < NCHUNK; ++c) {
        const _Float16* a1 = spk1 + (size_t)c * MR * Cc;
        gemm_lif<Cc,  false><<<grid, 512, 0, stream>>>(a1,   encHi, encLo, enc_b,      spkA, nullptr);
        gemm_lif<HID, false><<<grid, 512, 0, stream>>>(spkA, c0Hi,  c0Lo,  cell_b,     spkB, nullptr);
        gemm_lif<HID, true ><<<grid, 512, 0, stream>>>(spkB, c1Hi,  c1Lo,  cell_b+HID, nullptr,
                                                       out1 + (size_t)c * CH * HID);
    }

    mean_over_L<<<(Bb*HID + 255)/256, 256, 0, stream>>>(out1, out2);
}

// Round 4
// 629.524 us; speedup vs baseline: 4.2375x; 1.0420x over previous
//
#include <hip/hip_runtime.h>
#include <hip/hip_bf16.h>
#include <stdint.h>

#define Bb 32
#define Lx 512
#define Cc 256
#define Tt 4
#define HID 1024
#define RR (Bb*Lx)          // 16384 logical rows (b*L+l)
#define CH 4096             // rows r per chunk
#define MR (CH*Tt)          // 16384 interleaved rows (r*4+t) per chunk
#define NCHUNK (RR/CH)      // 4

typedef _Float16 half8 __attribute__((ext_vector_type(8)));
typedef float f32x4 __attribute__((ext_vector_type(4)));

// ---------------- async global->LDS, 16B per lane
__device__ __forceinline__ void gl16(const void* g, void* l) {
    __builtin_amdgcn_global_load_lds(
        (const __attribute__((address_space(1))) unsigned int*)g,
        (__attribute__((address_space(3))) unsigned int*)l, 16, 0, 0);
}
__device__ __forceinline__ void blockbar() {
    asm volatile("" ::: "memory");
    __builtin_amdgcn_s_barrier();
    asm volatile("" ::: "memory");
}
// one staging sweep: 512 threads x 16B = 128 rows x 64B, linear LDS dest,
// source slot pre-swizzled with the involution p ^ ((row>>1)&3)  (rule #21)
__device__ __forceinline__ void sweep(const _Float16* __restrict__ g, int K_,
                                      int rowBase, int ko, _Float16* dst8,
                                      int srow, int sslot) {
    gl16(g + (size_t)(rowBase + srow) * K_ + ko + sslot * 8, dst8);
}

// ---------------- weight split: w = hi + lo/2048 (exact to ~2^-22 rel)
__global__ void split_w(const float* __restrict__ w, _Float16* __restrict__ hi,
                        _Float16* __restrict__ lo, int n) {
    int i = blockIdx.x * 256 + threadIdx.x;
    if (i >= n) return;
    float x = w[i];
    _Float16 h = (_Float16)x;
    hi[i] = h;
    lo[i] = (_Float16)((x - (float)h) * 2048.0f);
}

// ---------------- Stage 1: conv(K=3 over L) + BN + LIF -> f16 spikes, rows r*4+t
__global__ void conv_bn_lif(const float* __restrict__ x,
                            const float* __restrict__ cw, const float* __restrict__ cb,
                            const float* __restrict__ g,  const float* __restrict__ be,
                            const float* __restrict__ mu, const float* __restrict__ var,
                            _Float16* __restrict__ spk) {   // [RR*4][Cc]
    int idx = blockIdx.x * blockDim.x + threadIdx.x;
    if (idx >= Bb*Lx*Cc) return;
    int bl = idx / Cc;
    int c  = idx % Cc;
    int l  = bl % Lx;
    float x0 = x[idx];
    float xm = (l > 0)    ? x[idx - Cc] : 0.0f;
    float xp = (l < Lx-1) ? x[idx + Cc] : 0.0f;
    float v = 0.0f;
    #pragma unroll
    for (int t = 0; t < Tt; ++t) {
        float y = cw[t*3+0]*xm + cw[t*3+1]*x0 + cw[t*3+2]*xp + cb[t];
        float inv = g[t] / sqrtf(var[t] + 1e-5f);
        y = (y - mu[t]) * inv + be[t];
        v = v + (y - v) * 0.5f;
        float s = (v >= 1.0f) ? 1.0f : 0.0f;
        spk[(size_t)(bl*4 + t)*Cc + c] = (_Float16)s;
        v = v * (1.0f - s);
    }
}

// ---------------- 4-phase deep-pipelined fused GEMM (hi/lo passes) + LIF epilogue
// Tile 256x256, BK=32, 8 waves (2M x 4N), per-wave 128x64.
// 4 K-tile LDS buffers, prefetch 3 tiles, vmcnt(8) once per tile (never 0 steady).
// Per phase: {frag ds_reads; 1 stage sweep; bar; lgkm0; setprio(1); 8 MFMA; setprio(0); bar}
template<int K, bool FINAL>
__global__ __launch_bounds__(512, 2)
void gemm_lif(const _Float16* __restrict__ A,
              const _Float16* __restrict__ Whi, const _Float16* __restrict__ Wlo,
              const float* __restrict__ bias,
              _Float16* __restrict__ spk_out, float* __restrict__ out_mean) {
    constexpr int KT  = K / 32;           // K-tiles per pass
    constexpr int NKT = 2 * KT;           // hi pass then lo pass
    __shared__ _Float16 lds[4 * 16384];   // 4 bufs x (A 8192 + B 8192 halfs) = 128 KB

    const int tid  = threadIdx.x;
    const int lane = tid & 63;
    const int wid  = tid >> 6;
    const int wm   = wid >> 2;        // 0..1
    const int wn   = wid & 3;         // 0..3
    const int m0   = blockIdx.x * 256;
    const int n0   = blockIdx.y * 256;

    const int fr  = lane & 15;
    const int lq  = lane >> 4;
    const int swq = (lq ^ ((fr >> 1) & 3)) * 8;      // conflict-free phys k-offset (halfs)
    const int srow  = tid >> 2;                       // staging row within sweep
    const int sslot = (tid & 3) ^ ((srow >> 1) & 3);  // pre-swizzled source slot

    f32x4 acc[8][4] = {};
    half8 af[8], bf[4];

    // ---- prologue: stage tiles 0,1,2 (all in hi pass since KT >= 8)
    #pragma unroll
    for (int t = 0; t < 3; ++t) {
        const int pb = t * 16384;
        const int ko = t * 32;
        sweep(A,   K, m0,       ko, &lds[pb +     0 + tid*8], srow, sslot);
        sweep(A,   K, m0 + 128, ko, &lds[pb +  4096 + tid*8], srow, sslot);
        sweep(Whi, K, n0,       ko, &lds[pb +  8192 + tid*8], srow, sslot);
        sweep(Whi, K, n0 + 128, ko, &lds[pb + 12288 + tid*8], srow, sslot);
    }

    #pragma unroll 1
    for (int kt = 0; kt < NKT; ++kt) {
        if (kt == KT) {   // pass boundary: finished hi accumulation
            #pragma unroll
            for (int i = 0; i < 8; ++i)
                #pragma unroll
                for (int j = 0; j < 4; ++j)
                    acc[i][j] *= 2048.0f;
        }
        if (kt < NKT-2)       asm volatile("s_waitcnt vmcnt(8)" ::: "memory");
        else if (kt == NKT-2) asm volatile("s_waitcnt vmcnt(4)" ::: "memory");
        else                  asm volatile("s_waitcnt vmcnt(0)" ::: "memory");
        blockbar();                               // tile kt landed for all waves

        const int cb = (kt & 3) * 16384;
        const int tp = kt + 3;
        const bool pre = (tp < NKT);
        const int pb = (tp & 3) * 16384;
        const _Float16* Wp = (tp >= KT) ? Wlo : Whi;
        const int kop = ((tp >= KT) ? tp - KT : tp) * 32;

        // ================= phase 1: af[0..3], bf[0..1] | stage A-h0 | MFMA iLo x jLo
        #pragma unroll
        for (int i = 0; i < 4; ++i)
            af[i] = *(const half8*)&lds[cb + (wm*128 + i*16 + fr)*32 + swq];
        #pragma unroll
        for (int j = 0; j < 2; ++j)
            bf[j] = *(const half8*)&lds[cb + 8192 + (wn*64 + j*16 + fr)*32 + swq];
        if (pre) sweep(A, K, m0, kop, &lds[pb + tid*8], srow, sslot);
        blockbar();
        asm volatile("s_waitcnt lgkmcnt(0)" ::: "memory");
        __builtin_amdgcn_sched_barrier(0);
        __builtin_amdgcn_s_setprio(1);
        #pragma unroll
        for (int i = 0; i < 4; ++i)
            #pragma unroll
            for (int j = 0; j < 2; ++j)
                acc[i][j] = __builtin_amdgcn_mfma_f32_16x16x32_f16(af[i], bf[j], acc[i][j], 0, 0, 0);
        __builtin_amdgcn_s_setprio(0);
        blockbar();

        // ================= phase 2: af[4..7] | stage A-h1 | MFMA iHi x jLo
        #pragma unroll
        for (int i = 4; i < 8; ++i)
            af[i] = *(const half8*)&lds[cb + (wm*128 + i*16 + fr)*32 + swq];
        if (pre) sweep(A, K, m0 + 128, kop, &lds[pb + 4096 + tid*8], srow, sslot);
        blockbar();
        asm volatile("s_waitcnt lgkmcnt(0)" ::: "memory");
        __builtin_amdgcn_sched_barrier(0);
        __builtin_amdgcn_s_setprio(1);
        #pragma unroll
        for (int i = 4; i < 8; ++i)
            #pragma unroll
            for (int j = 0; j < 2; ++j)
                acc[i][j] = __builtin_amdgcn_mfma_f32_16x16x32_f16(af[i], bf[j], acc[i][j], 0, 0, 0);
        __builtin_amdgcn_s_setprio(0);
        blockbar();

        // ================= phase 3: bf[2..3] | stage B-h0 | MFMA iLo x jHi
        #pragma unroll
        for (int j = 2; j < 4; ++j)
            bf[j] = *(const half8*)&lds[cb + 8192 + (wn*64 + j*16 + fr)*32 + swq];
        if (pre) sweep(Wp, K, n0, kop, &lds[pb + 8192 + tid*8], srow, sslot);
        blockbar();
        asm volatile("s_waitcnt lgkmcnt(0)" ::: "memory");
        __builtin_amdgcn_sched_barrier(0);
        __builtin_amdgcn_s_setprio(1);
        #pragma unroll
        for (int i = 0; i < 4; ++i)
            #pragma unroll
            for (int j = 2; j < 4; ++j)
                acc[i][j] = __builtin_amdgcn_mfma_f32_16x16x32_f16(af[i], bf[j], acc[i][j], 0, 0, 0);
        __builtin_amdgcn_s_setprio(0);
        blockbar();

        // ================= phase 4: (no reads) | stage B-h1 | MFMA iHi x jHi
        if (pre) sweep(Wp, K, n0 + 128, kop, &lds[pb + 12288 + tid*8], srow, sslot);
        __builtin_amdgcn_sched_barrier(0);
        __builtin_amdgcn_s_setprio(1);
        #pragma unroll
        for (int i = 4; i < 8; ++i)
            #pragma unroll
            for (int j = 2; j < 4; ++j)
                acc[i][j] = __builtin_amdgcn_mfma_f32_16x16x32_f16(af[i], bf[j], acc[i][j], 0, 0, 0);
        __builtin_amdgcn_s_setprio(0);
        // tile-top vmcnt+barrier of next iter closes this tile
    }

    // ---- epilogue: per-lane LIF over 4 acc regs (= 4 timesteps of one row)
    float bs[4];
    #pragma unroll
    for (int j = 0; j < 4; ++j)
        bs[j] = bias[n0 + wn*64 + j*16 + fr];
    const int rowq = lq * 4;
    #pragma unroll
    for (int i = 0; i < 8; ++i) {
        int rowLocal = m0 + wm*128 + i*16 + rowq;   // t=0 row; rows rowLocal..+3 = t 0..3
        int r = rowLocal >> 2;
        #pragma unroll
        for (int j = 0; j < 4; ++j) {
            int n = n0 + wn*64 + j*16 + fr;
            float v = 0.0f, ssum = 0.0f;
            #pragma unroll
            for (int t = 0; t < 4; ++t) {
                float xv = acc[i][j][t] * (1.0f/2048.0f) + bs[j];
                v = v + (xv - v) * 0.5f;
                float s = (v >= 1.0f) ? 1.0f : 0.0f;
                if constexpr (FINAL) ssum += s;
                else spk_out[(size_t)(rowLocal + t) * HID + n] = (_Float16)s;
                v = v * (1.0f - s);
            }
            if constexpr (FINAL) out_mean[(size_t)r * HID + n] = ssum * 0.25f;
        }
    }
}

// ---------------- out2[b,d] = mean over L of out1[b,l,d]
__global__ void mean_over_L(const float* __restrict__ out1, float* __restrict__ out2) {
    int idx = blockIdx.x * blockDim.x + threadIdx.x; // B*HID
    if (idx >= Bb*HID) return;
    int b = idx / HID, d = idx % HID;
    const float* p = out1 + (size_t)b*Lx*HID + d;
    float s = 0.0f;
    for (int l = 0; l < Lx; ++l) s += p[(size_t)l*HID];
    out2[idx] = s * (1.0f / Lx);
}

extern "C" void kernel_launch(void* const* d_in, const int* in_sizes, int n_in,
                              void* d_out, int out_size, void* d_ws, size_t ws_size,
                              hipStream_t stream) {
    const float* x      = (const float*)d_in[0];
    const float* cw     = (const float*)d_in[1];
    const float* cb     = (const float*)d_in[2];
    const float* g      = (const float*)d_in[3];
    const float* be     = (const float*)d_in[4];
    const float* mu     = (const float*)d_in[5];
    const float* var    = (const float*)d_in[6];
    const float* enc_w  = (const float*)d_in[7];
    const float* enc_b  = (const float*)d_in[8];
    const float* cell_w = (const float*)d_in[9];
    const float* cell_b = (const float*)d_in[10];

    float* out1 = (float*)d_out;                    // [RR][HID]
    float* out2 = out1 + (size_t)RR * HID;          // [B][HID]

    // ---- ws layout
    uint8_t* ws = (uint8_t*)d_ws;
    _Float16* spk1 = (_Float16*)ws;                               // RR*4*Cc f16 = 32 MB
    _Float16* spkA = (_Float16*)(ws + (size_t)32*1024*1024);      // MR*HID  f16 = 32 MB
    _Float16* spkB = (_Float16*)(ws + (size_t)64*1024*1024);      // MR*HID  f16 = 32 MB
    _Float16* wsp  = (_Float16*)(ws + (size_t)96*1024*1024);
    _Float16* encHi = wsp;                       // 1024*256
    _Float16* encLo = encHi + HID*Cc;
    _Float16* c0Hi  = encLo + HID*Cc;            // 1024*1024 each
    _Float16* c0Lo  = c0Hi + HID*HID;
    _Float16* c1Hi  = c0Lo + HID*HID;
    _Float16* c1Lo  = c1Hi + HID*HID;

    split_w<<<(HID*Cc + 255)/256, 256, 0, stream>>>(enc_w, encHi, encLo, HID*Cc);
    split_w<<<(HID*HID + 255)/256, 256, 0, stream>>>(cell_w, c0Hi, c0Lo, HID*HID);
    split_w<<<(HID*HID + 255)/256, 256, 0, stream>>>(cell_w + (size_t)HID*HID, c1Hi, c1Lo, HID*HID);

    conv_bn_lif<<<(Bb*Lx*Cc + 255)/256, 256, 0, stream>>>(x, cw, cb, g, be, mu, var, spk1);

    dim3 grid(MR/256, HID/256);   // 64 x 4 = 256 blocks = 1/CU
    for (int c = 0; c < NCHUNK; ++c) {
        const _Float16* a1 = spk1 + (size_t)c * MR * Cc;
        gemm_lif<Cc,  false><<<grid, 512, 0, stream>>>(a1,   encHi, encLo, enc_b,      spkA, nullptr);
        gemm_lif<HID, false><<<grid, 512, 0, stream>>>(spkA, c0Hi,  c0Lo,  cell_b,     spkB, nullptr);
        gemm_lif<HID, true ><<<grid, 512, 0, stream>>>(spkB, c1Hi,  c1Lo,  cell_b+HID, nullptr,
                                                       out1 + (size_t)c * CH * HID);
    }

    mean_over_L<<<(Bb*HID + 255)/256, 256, 0, stream>>>(out1, out2);
}

// Round 5
// 562.387 us; speedup vs baseline: 4.7433x; 1.1194x over previous
//
#include <hip/hip_runtime.h>
#include <hip/hip_bf16.h>
#include <stdint.h>

#define Bb 32
#define Lx 512
#define Cc 256
#define Tt 4
#define HID 1024
#define RR (Bb*Lx)          // 16384 logical rows (b*L+l)
#define CH 4096             // rows r per chunk
#define MR (CH*Tt)          // 16384 interleaved rows (r*4+t) per chunk
#define NCHUNK (RR/CH)      // 4

typedef _Float16 half8 __attribute__((ext_vector_type(8)));
typedef float f32x4 __attribute__((ext_vector_type(4)));

// ---------------- async global->LDS, 16B per lane
__device__ __forceinline__ void gl16(const void* g, void* l) {
    __builtin_amdgcn_global_load_lds(
        (const __attribute__((address_space(1))) unsigned int*)g,
        (__attribute__((address_space(3))) unsigned int*)l, 16, 0, 0);
}
__device__ __forceinline__ void blockbar() {
    asm volatile("" ::: "memory");
    __builtin_amdgcn_s_barrier();
    asm volatile("" ::: "memory");
}
// one staging sweep: 512 threads x 16B = 128 rows x 64B, linear LDS dest,
// source slot pre-swizzled with the involution p ^ ((row>>1)&3)  (rule #21)
__device__ __forceinline__ void sweep(const _Float16* __restrict__ g, int K_,
                                      int rowBase, int ko, _Float16* dst8,
                                      int srow, int sslot) {
    gl16(g + (size_t)(rowBase + srow) * K_ + ko + sslot * 8, dst8);
}

// ---------------- weight split: w = hi + lo/2048 (exact to ~2^-22 rel)
__global__ void split_w(const float* __restrict__ w, _Float16* __restrict__ hi,
                        _Float16* __restrict__ lo, int n) {
    int i = blockIdx.x * 256 + threadIdx.x;
    if (i >= n) return;
    float x = w[i];
    _Float16 h = (_Float16)x;
    hi[i] = h;
    lo[i] = (_Float16)((x - (float)h) * 2048.0f);
}

// ---------------- Stage 1: conv(K=3 over L) + BN + LIF -> f16 spikes, rows r*4+t
__global__ void conv_bn_lif(const float* __restrict__ x,
                            const float* __restrict__ cw, const float* __restrict__ cb,
                            const float* __restrict__ g,  const float* __restrict__ be,
                            const float* __restrict__ mu, const float* __restrict__ var,
                            _Float16* __restrict__ spk) {   // [RR*4][Cc]
    int idx = blockIdx.x * blockDim.x + threadIdx.x;
    if (idx >= Bb*Lx*Cc) return;
    int bl = idx / Cc;
    int c  = idx % Cc;
    int l  = bl % Lx;
    float x0 = x[idx];
    float xm = (l > 0)    ? x[idx - Cc] : 0.0f;
    float xp = (l < Lx-1) ? x[idx + Cc] : 0.0f;
    float v = 0.0f;
    #pragma unroll
    for (int t = 0; t < Tt; ++t) {
        float y = cw[t*3+0]*xm + cw[t*3+1]*x0 + cw[t*3+2]*xp + cb[t];
        float inv = g[t] / sqrtf(var[t] + 1e-5f);
        y = (y - mu[t]) * inv + be[t];
        v = v + (y - v) * 0.5f;
        float s = (v >= 1.0f) ? 1.0f : 0.0f;
        spk[(size_t)(bl*4 + t)*Cc + c] = (_Float16)s;
        v = v * (1.0f - s);
    }
}

// ---------------- deep-pipelined fused GEMM (hi/lo passes) + LIF epilogue
// Tile 256x256, BK=32, 8 waves (2M x 4N), per-wave 128x64.
// 4 K-tile LDS buffers, prefetch 3 tiles, vmcnt(8) once per tile (never 0 steady).
// Single barrier per K-tile; frag reads issued in operand order so the compiler's
// fine-grained lgkmcnt lets MFMA clusters overlap the LDS read/sweep stream.
template<int K, bool FINAL>
__global__ __launch_bounds__(512, 2)
void gemm_lif(const _Float16* __restrict__ A,
              const _Float16* __restrict__ Whi, const _Float16* __restrict__ Wlo,
              const float* __restrict__ bias,
              _Float16* __restrict__ spk_out, float* __restrict__ out_mean) {
    constexpr int KT  = K / 32;           // K-tiles per pass
    constexpr int NKT = 2 * KT;           // hi pass then lo pass
    __shared__ _Float16 lds[4 * 16384];   // 4 bufs x (A 8192 + B 8192 halfs) = 128 KB

    const int tid  = threadIdx.x;
    const int lane = tid & 63;
    const int wid  = tid >> 6;
    const int wm   = wid >> 2;        // 0..1
    const int wn   = wid & 3;         // 0..3
    const int m0   = blockIdx.x * 256;
    const int n0   = blockIdx.y * 256;

    const int fr  = lane & 15;
    const int lq  = lane >> 4;
    const int swq = (lq ^ ((fr >> 1) & 3)) * 8;      // conflict-free phys k-offset (halfs)
    const int srow  = tid >> 2;                       // staging row within sweep
    const int sslot = (tid & 3) ^ ((srow >> 1) & 3);  // pre-swizzled source slot

    f32x4 acc[8][4] = {};
    half8 af[8], bf[4];

    // ---- prologue: stage tiles 0,1,2 (all in hi pass since KT >= 8)
    #pragma unroll
    for (int t = 0; t < 3; ++t) {
        const int pb = t * 16384;
        const int ko = t * 32;
        sweep(A,   K, m0,       ko, &lds[pb +     0 + tid*8], srow, sslot);
        sweep(A,   K, m0 + 128, ko, &lds[pb +  4096 + tid*8], srow, sslot);
        sweep(Whi, K, n0,       ko, &lds[pb +  8192 + tid*8], srow, sslot);
        sweep(Whi, K, n0 + 128, ko, &lds[pb + 12288 + tid*8], srow, sslot);
    }

    #pragma unroll 1
    for (int kt = 0; kt < NKT; ++kt) {
        if (kt == KT) {   // pass boundary: finished hi accumulation
            #pragma unroll
            for (int i = 0; i < 8; ++i)
                #pragma unroll
                for (int j = 0; j < 4; ++j)
                    acc[i][j] *= 2048.0f;
        }
        if (kt < NKT-2)       asm volatile("s_waitcnt vmcnt(8)" ::: "memory");
        else if (kt == NKT-2) asm volatile("s_waitcnt vmcnt(4)" ::: "memory");
        else                  asm volatile("s_waitcnt vmcnt(0)" ::: "memory");
        blockbar();                               // tile kt landed for all waves

        const int cb = (kt & 3) * 16384;
        const int tp = kt + 3;
        const bool pre = (tp < NKT);
        const int pb = (tp & 3) * 16384;
        const _Float16* Wp = (tp >= KT) ? Wlo : Whi;
        const int kop = ((tp >= KT) ? tp - KT : tp) * 32;

        // ---- fragment reads, ordered so cluster 1's operands land first
        #pragma unroll
        for (int i = 0; i < 4; ++i)
            af[i] = *(const half8*)&lds[cb + (wm*128 + i*16 + fr)*32 + swq];
        #pragma unroll
        for (int j = 0; j < 2; ++j)
            bf[j] = *(const half8*)&lds[cb + 8192 + (wn*64 + j*16 + fr)*32 + swq];
        #pragma unroll
        for (int i = 4; i < 8; ++i)
            af[i] = *(const half8*)&lds[cb + (wm*128 + i*16 + fr)*32 + swq];
        #pragma unroll
        for (int j = 2; j < 4; ++j)
            bf[j] = *(const half8*)&lds[cb + 8192 + (wn*64 + j*16 + fr)*32 + swq];

        // ---- staging sweeps for tile kt+3 (buffer (kt-1)%4: readers done pre-barrier)
        if (pre) {
            sweep(A,  K, m0,       kop, &lds[pb +     0 + tid*8], srow, sslot);
            sweep(A,  K, m0 + 128, kop, &lds[pb +  4096 + tid*8], srow, sslot);
            sweep(Wp, K, n0,       kop, &lds[pb +  8192 + tid*8], srow, sslot);
            sweep(Wp, K, n0 + 128, kop, &lds[pb + 12288 + tid*8], srow, sslot);
        }

        // ---- 32 MFMA in 4 clusters; compiler inserts counted lgkm waits per cluster
        __builtin_amdgcn_s_setprio(1);
        #pragma unroll
        for (int i = 0; i < 4; ++i)
            #pragma unroll
            for (int j = 0; j < 2; ++j)
                acc[i][j] = __builtin_amdgcn_mfma_f32_16x16x32_f16(af[i], bf[j], acc[i][j], 0, 0, 0);
        #pragma unroll
        for (int i = 4; i < 8; ++i)
            #pragma unroll
            for (int j = 0; j < 2; ++j)
                acc[i][j] = __builtin_amdgcn_mfma_f32_16x16x32_f16(af[i], bf[j], acc[i][j], 0, 0, 0);
        #pragma unroll
        for (int i = 0; i < 4; ++i)
            #pragma unroll
            for (int j = 2; j < 4; ++j)
                acc[i][j] = __builtin_amdgcn_mfma_f32_16x16x32_f16(af[i], bf[j], acc[i][j], 0, 0, 0);
        #pragma unroll
        for (int i = 4; i < 8; ++i)
            #pragma unroll
            for (int j = 2; j < 4; ++j)
                acc[i][j] = __builtin_amdgcn_mfma_f32_16x16x32_f16(af[i], bf[j], acc[i][j], 0, 0, 0);
        __builtin_amdgcn_s_setprio(0);
    }

    // ---- epilogue: per-lane LIF over 4 acc regs (= 4 timesteps of one row)
    float bs[4];
    #pragma unroll
    for (int j = 0; j < 4; ++j)
        bs[j] = bias[n0 + wn*64 + j*16 + fr];
    const int rowq = lq * 4;
    #pragma unroll
    for (int i = 0; i < 8; ++i) {
        int rowLocal = m0 + wm*128 + i*16 + rowq;   // t=0 row; rows rowLocal..+3 = t 0..3
        int r = rowLocal >> 2;
        #pragma unroll
        for (int j = 0; j < 4; ++j) {
            int n = n0 + wn*64 + j*16 + fr;
            float v = 0.0f, ssum = 0.0f;
            #pragma unroll
            for (int t = 0; t < 4; ++t) {
                float xv = acc[i][j][t] * (1.0f/2048.0f) + bs[j];
                v = v + (xv - v) * 0.5f;
                float s = (v >= 1.0f) ? 1.0f : 0.0f;
                if constexpr (FINAL) ssum += s;
                else spk_out[(size_t)(rowLocal + t) * HID + n] = (_Float16)s;
                v = v * (1.0f - s);
            }
            if constexpr (FINAL) out_mean[(size_t)r * HID + n] = ssum * 0.25f;
        }
    }
}

// ---------------- out2[b,d] = mean over L of out1[b,l,d]
__global__ void mean_over_L(const float* __restrict__ out1, float* __restrict__ out2) {
    int idx = blockIdx.x * blockDim.x + threadIdx.x; // B*HID
    if (idx >= Bb*HID) return;
    int b = idx / HID, d = idx % HID;
    const float* p = out1 + (size_t)b*Lx*HID + d;
    float s = 0.0f;
    for (int l = 0; l < Lx; ++l) s += p[(size_t)l*HID];
    out2[idx] = s * (1.0f / Lx);
}

extern "C" void kernel_launch(void* const* d_in, const int* in_sizes, int n_in,
                              void* d_out, int out_size, void* d_ws, size_t ws_size,
                              hipStream_t stream) {
    const float* x      = (const float*)d_in[0];
    const float* cw     = (const float*)d_in[1];
    const float* cb     = (const float*)d_in[2];
    const float* g      = (const float*)d_in[3];
    const float* be     = (const float*)d_in[4];
    const float* mu     = (const float*)d_in[5];
    const float* var    = (const float*)d_in[6];
    const float* enc_w  = (const float*)d_in[7];
    const float* enc_b  = (const float*)d_in[8];
    const float* cell_w = (const float*)d_in[9];
    const float* cell_b = (const float*)d_in[10];

    float* out1 = (float*)d_out;                    // [RR][HID]
    float* out2 = out1 + (size_t)RR * HID;          // [B][HID]

    // ---- ws layout
    uint8_t* ws = (uint8_t*)d_ws;
    _Float16* spk1 = (_Float16*)ws;                               // RR*4*Cc f16 = 32 MB
    _Float16* spkA = (_Float16*)(ws + (size_t)32*1024*1024);      // MR*HID  f16 = 32 MB
    _Float16* spkB = (_Float16*)(ws + (size_t)64*1024*1024);      // MR*HID  f16 = 32 MB
    _Float16* wsp  = (_Float16*)(ws + (size_t)96*1024*1024);
    _Float16* encHi = wsp;                       // 1024*256
    _Float16* encLo = encHi + HID*Cc;
    _Float16* c0Hi  = encLo + HID*Cc;            // 1024*1024 each
    _Float16* c0Lo  = c0Hi + HID*HID;
    _Float16* c1Hi  = c0Lo + HID*HID;
    _Float16* c1Lo  = c1Hi + HID*HID;

    split_w<<<(HID*Cc + 255)/256, 256, 0, stream>>>(enc_w, encHi, encLo, HID*Cc);
    split_w<<<(HID*HID + 255)/256, 256, 0, stream>>>(cell_w, c0Hi, c0Lo, HID*HID);
    split_w<<<(HID*HID + 255)/256, 256, 0, stream>>>(cell_w + (size_t)HID*HID, c1Hi, c1Lo, HID*HID);

    conv_bn_lif<<<(Bb*Lx*Cc + 255)/256, 256, 0, stream>>>(x, cw, cb, g, be, mu, var, spk1);

    dim3 grid(MR/256, HID/256);   // 64 x 4 = 256 blocks = 1/CU
    for (int c = 0; c < NCHUNK; ++c) {
        const _Float16* a1 = spk1 + (size_t)c * MR * Cc;
        gemm_lif<Cc,  false><<<grid, 512, 0, stream>>>(a1,   encHi, encLo, enc_b,      spkA, nullptr);
        gemm_lif<HID, false><<<grid, 512, 0, stream>>>(spkA, c0Hi,  c0Lo,  cell_b,     spkB, nullptr);
        gemm_lif<HID, true ><<<grid, 512, 0, stream>>>(spkB, c1Hi,  c1Lo,  cell_b+HID, nullptr,
                                                       out1 + (size_t)c * CH * HID);
    }

    mean_over_L<<<(Bb*HID + 255)/256, 256, 0, stream>>>(out1, out2);
}

// Round 6
// 534.792 us; speedup vs baseline: 4.9881x; 1.0516x over previous
//
#include <hip/hip_runtime.h>
#include <hip/hip_bf16.h>
#include <stdint.h>

#define Bb 32
#define Lx 512
#define Cc 256
#define Tt 4
#define HID 1024
#define RR (Bb*Lx)          // 16384 logical rows (b*L+l)
#define CH 8192             // rows r per chunk
#define MR (CH*Tt)          // 32768 interleaved rows (r*4+t) per chunk
#define NCHUNK (RR/CH)      // 2

typedef int i32x4 __attribute__((ext_vector_type(4)));

// ---------------- async global->LDS, 16B per lane
__device__ __forceinline__ void gl16(const void* g, void* l) {
    __builtin_amdgcn_global_load_lds(
        (const __attribute__((address_space(1))) unsigned int*)g,
        (__attribute__((address_space(3))) unsigned int*)l, 16, 0, 0);
}
__device__ __forceinline__ void blockbar() {
    asm volatile("" ::: "memory");
    __builtin_amdgcn_s_barrier();
    asm volatile("" ::: "memory");
}

// stage one 256row x 128B i8 operand tile into LDS as 2 k-planes x 2 row-halves.
// Linear LDS dest; source slot pre-swizzled with involution slot^((row>>1)&3)
// (rule #21) so swizzled ds_reads see logical data. 4 x gl16 per thread.
__device__ __forceinline__ void stage_tile_i8(const int8_t* __restrict__ g, int K_,
                                              int rowBase, int ko, int8_t* ldsBase,
                                              int tid) {
    const int row = tid >> 2;                    // 0..127 within half
    const int sl  = (tid & 3) ^ ((row >> 1) & 3);
    #pragma unroll
    for (int h = 0; h < 2; ++h)
        #pragma unroll
        for (int p = 0; p < 2; ++p)
            gl16(g + (size_t)(rowBase + h*128 + row) * K_ + ko + p*64 + sl*16,
                 ldsBase + p*16384 + h*8192 + tid*16);
}

// ---------------- weight quantization: w*2^s = i1*2^14 + i2*2^7 + i3 (exact fixed point)
__global__ void zero_f(float* p, int n) {
    if ((int)threadIdx.x < n) p[threadIdx.x] = 0.0f;
}
__global__ void absmax_k(const float* __restrict__ w, int n, float* __restrict__ out) {
    float v = 0.0f;
    for (int i = blockIdx.x*256 + threadIdx.x; i < n; i += gridDim.x*256)
        v = fmaxf(v, fabsf(w[i]));
    #pragma unroll
    for (int o = 32; o; o >>= 1) v = fmaxf(v, __shfl_down(v, o));
    if ((threadIdx.x & 63) == 0)
        atomicMax((unsigned*)out, __float_as_uint(v));   // positives: bit-max == val-max
}
__global__ void quant_k(const float* __restrict__ w, int n,
                        const float* __restrict__ amax,
                        int8_t* __restrict__ q, float* __restrict__ invOut) {
    float m = fmaxf(amax[0], 1e-20f);
    float e = floorf(log2f(126.0f * 16384.0f / m));
    float sp = exp2f(e);
    if (m * sp > 126.0f * 16384.0f) sp *= 0.5f;     // guard log2 boundary
    if (blockIdx.x == 0 && threadIdx.x == 0) invOut[0] = 1.0f / sp;
    int i = blockIdx.x*256 + threadIdx.x;
    if (i >= n) return;
    float v  = rintf(w[i] * sp);                    // |v| <= 126*2^14, integer-exact in f32
    float i1 = rintf(v * (1.0f/16384.0f));          // |i1| <= 126
    float r1 = v - i1 * 16384.0f;                   // |r1| <= 2^13, exact
    float i2 = rintf(r1 * (1.0f/128.0f));           // |i2| <= 64
    float r2 = r1 - i2 * 128.0f;                    // |r2| <= 64, exact
    q[i]               = (int8_t)i1;
    q[(size_t)n + i]   = (int8_t)i2;
    q[(size_t)2*n + i] = (int8_t)r2;
}

// ---------------- Stage 1: conv(K=3 over L) + BN + LIF -> i8 spikes, rows r*4+t
__global__ void conv_bn_lif(const float* __restrict__ x,
                            const float* __restrict__ cw, const float* __restrict__ cb,
                            const float* __restrict__ g,  const float* __restrict__ be,
                            const float* __restrict__ mu, const float* __restrict__ var,
                            int8_t* __restrict__ spk) {   // [RR*4][Cc]
    int idx = blockIdx.x * blockDim.x + threadIdx.x;
    if (idx >= Bb*Lx*Cc) return;
    int bl = idx / Cc;
    int c  = idx % Cc;
    int l  = bl % Lx;
    float x0 = x[idx];
    float xm = (l > 0)    ? x[idx - Cc] : 0.0f;
    float xp = (l < Lx-1) ? x[idx + Cc] : 0.0f;
    float v = 0.0f;
    #pragma unroll
    for (int t = 0; t < Tt; ++t) {
        float y = cw[t*3+0]*xm + cw[t*3+1]*x0 + cw[t*3+2]*xp + cb[t];
        float inv = g[t] / sqrtf(var[t] + 1e-5f);
        y = (y - mu[t]) * inv + be[t];
        v = v + (y - v) * 0.5f;
        float s = (v >= 1.0f) ? 1.0f : 0.0f;
        spk[(size_t)(bl*4 + t)*Cc + c] = (int8_t)s;
        v = v * (1.0f - s);
    }
}

// ---------------- i8 3-pass deep-pipelined fused GEMM + LIF epilogue
// Tile 256x256, BK=128 bytes (two 64B k-planes), 8 waves (2M x 4N), wave tile 128x64.
// 2 LDS buffers (128 KB); sweeps for tile kt+1 issued right after tile-kt barrier
// (one full tile ahead of their vmcnt(0)) -> drain is free; 1 barrier per 128 K.
// acc runs acc = (acc1*128 + acc2)*128 + acc3 in exact i32 (|acc| < 2^31 proven).
template<int K, bool FINAL>
__global__ __launch_bounds__(512, 2)
void gemm_lif(const int8_t* __restrict__ A,
              const int8_t* __restrict__ Wq,      // [3 comps][HID][K]
              const float* __restrict__ invs,     // [1] 2^-s
              const float* __restrict__ bias,
              int8_t* __restrict__ spk_out, float* __restrict__ out_mean) {
    constexpr int KT  = K / 128;          // tiles per pass
    constexpr int NKT = 3 * KT;           // three fixed-point component passes
    __shared__ int8_t lds[2 * 65536];     // 2 bufs x (A 32KB + B 32KB)

    const int tid  = threadIdx.x;
    const int lane = tid & 63;
    const int wid  = tid >> 6;
    const int wm   = wid >> 2;        // 0..1
    const int wn   = wid & 3;         // 0..3
    const int m0   = blockIdx.x * 256;
    const int n0   = blockIdx.y * 256;
    const int fr   = lane & 15;
    const int lq   = lane >> 4;
    const int swq  = (lq ^ ((fr >> 1) & 3)) * 16;   // conflict-free phys byte offset in 64B row

    i32x4 acc[8][4] = {};
    i32x4 af[8], bf[4];

    // ---- prologue: stage tile 0 (component 0, ko 0) into buf0
    stage_tile_i8(A,  K, m0, 0, &lds[0],     tid);
    stage_tile_i8(Wq, K, n0, 0, &lds[32768], tid);

    #pragma unroll 1
    for (int kt = 0; kt < NKT; ++kt) {
        if (kt == KT || kt == 2*KT) {     // component boundary: shift accumulated value
            #pragma unroll
            for (int i = 0; i < 8; ++i)
                #pragma unroll
                for (int j = 0; j < 4; ++j)
                    acc[i][j] *= 128;
        }
        asm volatile("s_waitcnt vmcnt(0)" ::: "memory");   // tile kt landed (issued 1 tile ago)
        blockbar();

        const int cb = (kt & 1) * 65536;
        // ---- issue sweeps for tile kt+1 into the other buffer (its readers are
        //      retired: all waves passed this barrier after finishing tile kt-1)
        if (kt + 1 < NKT) {
            const int t1 = kt + 1;
            const int pb = (t1 & 1) * 65536;
            const int ko = (t1 % KT) * 128;
            const int8_t* Wc = Wq + (size_t)(t1 / KT) * HID * K;
            stage_tile_i8(A,  K, m0, ko, &lds[pb],         tid);
            stage_tile_i8(Wc, K, n0, ko, &lds[pb + 32768], tid);
        }

        // ---- two k-planes: 12 ds_read_b128 + 32 MFMA each; compiler inserts counted lgkm
        #pragma unroll
        for (int p = 0; p < 2; ++p) {
            const int8_t* lA = &lds[cb + p*16384];
            const int8_t* lB = &lds[cb + 32768 + p*16384];
            #pragma unroll
            for (int i = 0; i < 8; ++i)
                af[i] = *(const i32x4*)&lA[(wm*128 + i*16 + fr)*64 + swq];
            #pragma unroll
            for (int j = 0; j < 4; ++j)
                bf[j] = *(const i32x4*)&lB[(wn*64 + j*16 + fr)*64 + swq];
            __builtin_amdgcn_s_setprio(1);
            #pragma unroll
            for (int i = 0; i < 8; ++i)
                #pragma unroll
                for (int j = 0; j < 4; ++j)
                    acc[i][j] = __builtin_amdgcn_mfma_i32_16x16x64_i8(af[i], bf[j], acc[i][j], 0, 0, 0);
            __builtin_amdgcn_s_setprio(0);
        }
    }

    // ---- epilogue: per-lane LIF over 4 acc regs (= 4 timesteps of one row)
    const float inv = invs[0];
    float bs[4];
    #pragma unroll
    for (int j = 0; j < 4; ++j)
        bs[j] = bias[n0 + wn*64 + j*16 + fr];
    const int rowq = lq * 4;
    #pragma unroll
    for (int i = 0; i < 8; ++i) {
        int rowLocal = m0 + wm*128 + i*16 + rowq;   // t=0 row; rows rowLocal..+3 = t 0..3
        int r = rowLocal >> 2;
        #pragma unroll
        for (int j = 0; j < 4; ++j) {
            int n = n0 + wn*64 + j*16 + fr;
            float v = 0.0f, ssum = 0.0f;
            #pragma unroll
            for (int t = 0; t < 4; ++t) {
                float xv = (float)acc[i][j][t] * inv + bs[j];
                v = v + (xv - v) * 0.5f;
                float s = (v >= 1.0f) ? 1.0f : 0.0f;
                if constexpr (FINAL) ssum += s;
                else spk_out[(size_t)(rowLocal + t) * HID + n] = (int8_t)s;
                v = v * (1.0f - s);
            }
            if constexpr (FINAL) out_mean[(size_t)r * HID + n] = ssum * 0.25f;
        }
    }
}

// ---------------- out2[b,d] = mean over L of out1[b,l,d]
__global__ void mean_over_L(const float* __restrict__ out1, float* __restrict__ out2) {
    int idx = blockIdx.x * blockDim.x + threadIdx.x; // B*HID
    if (idx >= Bb*HID) return;
    int b = idx / HID, d = idx % HID;
    const float* p = out1 + (size_t)b*Lx*HID + d;
    float s = 0.0f;
    for (int l = 0; l < Lx; ++l) s += p[(size_t)l*HID];
    out2[idx] = s * (1.0f / Lx);
}

extern "C" void kernel_launch(void* const* d_in, const int* in_sizes, int n_in,
                              void* d_out, int out_size, void* d_ws, size_t ws_size,
                              hipStream_t stream) {
    const float* x      = (const float*)d_in[0];
    const float* cw     = (const float*)d_in[1];
    const float* cb     = (const float*)d_in[2];
    const float* g      = (const float*)d_in[3];
    const float* be     = (const float*)d_in[4];
    const float* mu     = (const float*)d_in[5];
    const float* var    = (const float*)d_in[6];
    const float* enc_w  = (const float*)d_in[7];
    const float* enc_b  = (const float*)d_in[8];
    const float* cell_w = (const float*)d_in[9];
    const float* cell_b = (const float*)d_in[10];

    float* out1 = (float*)d_out;                    // [RR][HID]
    float* out2 = out1 + (size_t)RR * HID;          // [B][HID]

    // ---- ws layout (~88 MB total)
    int8_t* spk1 = (int8_t*)d_ws;                   // RR*4*Cc = 16 MB
    int8_t* spkA = spk1 + (size_t)RR*4*Cc;          // MR*HID  = 32 MB
    int8_t* spkB = spkA + (size_t)MR*HID;           // MR*HID  = 32 MB
    int8_t* qEnc = spkB + (size_t)MR*HID;           // 3*HID*Cc
    int8_t* qC0  = qEnc + (size_t)3*HID*Cc;         // 3*HID*HID
    int8_t* qC1  = qC0  + (size_t)3*HID*HID;        // 3*HID*HID
    float*  amax = (float*)(qC1 + (size_t)3*HID*HID);
    float*  invv = amax + 3;

    // ---- weight quantization (exact 21-bit fixed point, per-matrix pow2 scale)
    zero_f<<<1, 4, 0, stream>>>(amax, 3);
    absmax_k<<<512, 256, 0, stream>>>(enc_w,  HID*Cc,  amax + 0);
    absmax_k<<<512, 256, 0, stream>>>(cell_w, HID*HID, amax + 1);
    absmax_k<<<512, 256, 0, stream>>>(cell_w + (size_t)HID*HID, HID*HID, amax + 2);
    quant_k<<<(HID*Cc  + 255)/256, 256, 0, stream>>>(enc_w,  HID*Cc,  amax + 0, qEnc, invv + 0);
    quant_k<<<(HID*HID + 255)/256, 256, 0, stream>>>(cell_w, HID*HID, amax + 1, qC0,  invv + 1);
    quant_k<<<(HID*HID + 255)/256, 256, 0, stream>>>(cell_w + (size_t)HID*HID, HID*HID, amax + 2, qC1, invv + 2);

    // ---- conv + BN + LIF
    conv_bn_lif<<<(Bb*Lx*Cc + 255)/256, 256, 0, stream>>>(x, cw, cb, g, be, mu, var, spk1);

    // ---- chunked trunk (2 chunks of 8192 rows)
    dim3 grid(MR/256, HID/256);   // 128 x 4 = 512 blocks
    for (int c = 0; c < NCHUNK; ++c) {
        const int8_t* a1 = spk1 + (size_t)c * MR * Cc;
        gemm_lif<Cc,  false><<<grid, 512, 0, stream>>>(a1,   qEnc, invv + 0, enc_b,      spkA, nullptr);
        gemm_lif<HID, false><<<grid, 512, 0, stream>>>(spkA, qC0,  invv + 1, cell_b,     spkB, nullptr);
        gemm_lif<HID, true ><<<grid, 512, 0, stream>>>(spkB, qC1,  invv + 2, cell_b+HID, nullptr,
                                                       out1 + (size_t)c * CH * HID);
    }

    mean_over_L<<<(Bb*HID + 255)/256, 256, 0, stream>>>(out1, out2);
}